// Round 10
// baseline (466.137 us; speedup 1.0000x reference)
//
#include <hip/hip_runtime.h>
#include <hip/hip_bf16.h>

#define SEQ 256
#define BATCH 4096
#define DD 100
#define SB (BATCH * DD)             // floats between s-planes
#define NBCOL 4                     // batch columns per block
#define SCH 16                      // s-planes per chunk
#define NCHUNK (SEQ / SCH)          // 16
#define ROWS (SCH * NBCOL)          // 64 rows per chunk (row = s_local*4 + b_local)
#define SLAB_B (NBCOL * DD * 4)     // 1600 B per s-slab (contiguous global AND LDS)
#define CH_BYTES (ROWS * DD * 4)    // 25600 B per chunk

typedef __attribute__((ext_vector_type(8))) short bf16x8;
typedef __attribute__((ext_vector_type(4))) float f32x4;
typedef __attribute__((ext_vector_type(4))) unsigned u32x4;

#define WAIT_VM0  asm volatile("s_waitcnt vmcnt(0)" ::: "memory")
#define WAIT_LGKM asm volatile("s_waitcnt lgkmcnt(0)" ::: "memory")

__device__ __forceinline__ short f2bf(float x) {
    __hip_bfloat16 hv = __float2bfloat16(x);
    return *reinterpret_cast<short*>(&hv);
}
// accurate tanh (outer only; 4 uses/wave/chunk)
__device__ __forceinline__ float fast_tanh(float x) {
    float ax = fabsf(x);
    float e  = __expf(-2.0f * ax);
    float t  = (1.0f - e) * __builtin_amdgcn_rcpf(1.0f + e);
    return copysignf(t, x);
}
// Pade(3,2) tanh, clamped (inner activations; error budget ok vs 9.2e-2 threshold)
__device__ __forceinline__ float pade_tanh(float x) {
    const float x2  = x * x;
    const float num = x * (27.0f + x2);
    const float den = fmaf(9.0f, x2, 27.0f);
    const float t   = num * __builtin_amdgcn_rcpf(den);
    return fminf(1.0f, fmaxf(-1.0f, t));
}
// (bf16(hi)<<16) | bf16(lo), truncating — one v_perm_b32
__device__ __forceinline__ unsigned pack_bf2(float lo, float hi) {
    return __builtin_amdgcn_perm(__builtin_bit_cast(unsigned, hi),
                                 __builtin_bit_cast(unsigned, lo),
                                 0x07060302u);
}

// ---- prep: pack W [DD x DD] fp32 -> MFMA B-fragments (bf16, zero-padded) ----
// frag (n,t): cols [16n,16n+16), k [32t,32t+32). lane l: col = 16n+(l&15),
// k = 32t + 8*(l>>4) + e. Layout verified rounds 2-9.
__global__ void prep_wfrag(const float* __restrict__ W, uint4* __restrict__ wsf) {
    const int idx = blockIdx.x * 256 + threadIdx.x;
    if (idx >= 28 * 64) return;
    const int l  = idx & 63;
    const int ft = idx >> 6;
    const int t  = ft & 3;
    const int n  = ft >> 2;
    const int col   = 16 * n + (l & 15);
    const int kbase = 32 * t + 8 * (l >> 4);
    unsigned short v[8];
    #pragma unroll
    for (int e = 0; e < 8; ++e) {
        const int k = kbase + e;
        const float w = (col < DD && k < DD) ? W[k * DD + col] : 0.0f;
        v[e] = (unsigned short)f2bf(w);
    }
    uint4 u;
    u.x = (unsigned)v[0] | ((unsigned)v[1] << 16);
    u.y = (unsigned)v[2] | ((unsigned)v[3] << 16);
    u.z = (unsigned)v[4] | ((unsigned)v[5] << 16);
    u.w = (unsigned)v[6] | ((unsigned)v[7] << 16);
    wsf[ft * 64 + l] = u;
}

// Direct global->LDS staging of one 25600B chunk, 7 loads per wave (uniform):
//  - 24 slots of 1KB (64 lanes x 16B): slot q = wid + 4r, r = 0..5
//  - final 1KB split 4 ways: 256B per wave (64 lanes x 4B)
__device__ __forceinline__ void stage_chunk(const float* __restrict__ f,
                                            int s0, int b0, float* lbase,
                                            int wid, int lane) {
    #pragma unroll
    for (int r = 0; r < 6; ++r) {
        const int q   = wid + 4 * r;               // 0..23, wave-uniform
        const int L   = (q << 10) + (lane << 4);
        const int s   = L / SLAB_B;
        const int rem = L - s * SLAB_B;
        const float* gp = f + (size_t)(s0 + s) * SB + (size_t)b0 * DD + (rem >> 2);
        __builtin_amdgcn_global_load_lds(
            (const __attribute__((address_space(1))) void*)gp,
            (__attribute__((address_space(3))) void*)((char*)lbase + L),
            16, 0, 0);
    }
    {   // tail: bytes 24576..25599
        const int L   = 24 * 1024 + wid * 256 + lane * 4;
        const int s   = L / SLAB_B;
        const int rem = L - s * SLAB_B;
        const float* gp = f + (size_t)(s0 + s) * SB + (size_t)b0 * DD + (rem >> 2);
        __builtin_amdgcn_global_load_lds(
            (const __attribute__((address_space(1))) void*)gp,
            (__attribute__((address_space(3))) void*)((char*)lbase + L),
            4, 0, 0);
    }
}

__global__ __launch_bounds__(256, 3)
void fused_sent_attn(const float* __restrict__ f,     // [SEQ, BATCH, DD]
                     const uint4* __restrict__ wsf,   // packed W frags (28*64)
                     const float* __restrict__ bias,  // [DD]
                     const float* __restrict__ cw,    // [DD]
                     const float* __restrict__ h,     // [2, BATCH, 50]
                     float* __restrict__ out)         // [pooled | h]
{
    __shared__ __align__(16) float fs[2][ROWS * DD];  // 51,200 B double buffer
    __shared__ uint4 wlds3[7 * 16];                   // 1,792 B (t=3 frags, validated r6)
    __shared__ float wexp[ROWS];
    __shared__ float den_s[NBCOL];

    const int tid  = threadIdx.x;
    const int lane = tid & 63;
    const int wid  = tid >> 6;
    const int lr   = lane & 15;
    const int g    = lane >> 4;
    const int b0   = blockIdx.x * NBCOL;

    // ---- prologue: t3 W-frags -> LDS; bias/cw regs; h passthrough ----
    if (tid < 7 * 16) wlds3[tid] = wsf[(4 * (tid >> 4) + 3) * 64 + (tid & 15)];

    float bias_r[7], cw_r[7];
    #pragma unroll
    for (int n = 0; n < 7; ++n) {
        const int c = 16 * n + lr;
        bias_r[n] = (c < DD) ? bias[c] : 0.0f;
        cw_r[n]   = (c < DD) ? cw[c]   : 0.0f;
    }
    {   // h: this block's 4 columns, both halves; 100 x float4
        const size_t obase = (size_t)BATCH * DD;
        const size_t HB = (size_t)BATCH * 50;
        if (tid < 100) {
            const int half = tid / 50, rem = tid - 50 * half;
            const float4* hs = reinterpret_cast<const float4*>(h + half * HB + (size_t)b0 * 50);
            float4* od = reinterpret_cast<float4*>(out + obase + half * HB + (size_t)b0 * 50);
            od[rem] = hs[rem];
        }
    }

    // ---- W fragments t=0..2 -> registers (wave-invariant, 84 VGPR) ----
    bf16x8 wr[21];
    #pragma unroll
    for (int n = 0; n < 7; ++n)
        #pragma unroll
        for (int t = 0; t < 3; ++t)
            wr[3 * n + t] = *reinterpret_cast<const bf16x8*>(&wsf[(4 * n + t) * 64 + lane]);
    WAIT_VM0;                       // wr + h-stores + bias/cw drained

    // ---- stage chunk 0, wait, sync ----
    stage_chunk(f, 0, b0, fs[0], wid, lane);
    WAIT_VM0;
    WAIT_LGKM;                      // wlds3 ds_writes done
    __builtin_amdgcn_s_barrier();
    __builtin_amdgcn_sched_barrier(0);

    // pooling ownership: 100 threads x (col pb, float4-quad q4); 4 denom threads
    const int pb = tid / 25, q4 = tid % 25;
    const bool pact = (tid < 100);
    f32x4 pacc = {0.0f, 0.0f, 0.0f, 0.0f};
    float dreg = 0.0f;

    int cur = 0;
    for (int jc = 0; jc < NCHUNK; ++jc) {
        // ---- 1. issue next chunk into the other buffer (unsinkable) ----
        if (jc + 1 < NCHUNK)
            stage_chunk(f, (jc + 1) * SCH, b0, fs[cur ^ 1], wid, lane);

        // ---- 2. scores: wave owns rows 16*wid..16*wid+15 of chunk jc ----
        {
            const float* rp = &fs[cur][(16 * wid + lr) * DD];
            bf16x8 a[4];
            #pragma unroll
            for (int t = 0; t < 3; ++t) {
                const float4 u0 = *reinterpret_cast<const float4*>(rp + 32 * t + 8 * g);
                const float4 u1 = *reinterpret_cast<const float4*>(rp + 32 * t + 8 * g + 4);
                u32x4 pk = {pack_bf2(u0.x, u0.y), pack_bf2(u0.z, u0.w),
                            pack_bf2(u1.x, u1.y), pack_bf2(u1.z, u1.w)};
                a[t] = __builtin_bit_cast(bf16x8, pk);
            }
            {
                u32x4 pk = {0u, 0u, 0u, 0u};
                if (g == 0) {
                    const float4 u0 = *reinterpret_cast<const float4*>(rp + 96);
                    pk.x = pack_bf2(u0.x, u0.y);
                    pk.y = pack_bf2(u0.z, u0.w);
                }
                a[3] = __builtin_bit_cast(bf16x8, pk);
            }

            float scp[4] = {0, 0, 0, 0};
            #pragma unroll
            for (int n = 0; n < 7; ++n) {
                bf16x8 b3 = {0, 0, 0, 0, 0, 0, 0, 0};
                if (g == 0) b3 = *reinterpret_cast<const bf16x8*>(&wlds3[16 * n + lr]);
                f32x4 acc = {bias_r[n], bias_r[n], bias_r[n], bias_r[n]};
                acc = __builtin_amdgcn_mfma_f32_16x16x32_bf16(a[0], wr[3 * n + 0], acc, 0, 0, 0);
                acc = __builtin_amdgcn_mfma_f32_16x16x32_bf16(a[1], wr[3 * n + 1], acc, 0, 0, 0);
                acc = __builtin_amdgcn_mfma_f32_16x16x32_bf16(a[2], wr[3 * n + 2], acc, 0, 0, 0);
                acc = __builtin_amdgcn_mfma_f32_16x16x32_bf16(a[3], b3,            acc, 0, 0, 0);
                #pragma unroll
                for (int r = 0; r < 4; ++r)
                    scp[r] = fmaf(pade_tanh(acc[r]), cw_r[n], scp[r]);
            }
            #pragma unroll
            for (int r = 0; r < 4; ++r) {
                float v = scp[r];
                v += __shfl_xor(v, 1);
                v += __shfl_xor(v, 2);
                v += __shfl_xor(v, 4);
                v += __shfl_xor(v, 8);
                if (lr == 0)
                    wexp[16 * wid + 4 * g + r] = __expf(fast_tanh(v));
            }
        }
        WAIT_LGKM;                        // wexp ds_writes done
        __builtin_amdgcn_s_barrier();     // B1: wexp visible
        __builtin_amdgcn_sched_barrier(0);

        // ---- 3. pooled numerator + denominator ----
        if (pact) {
            #pragma unroll
            for (int s = 0; s < SCH; ++s) {
                const float w = wexp[s * NBCOL + pb];
                const f32x4 v = *reinterpret_cast<const f32x4*>(
                    &fs[cur][(s * NBCOL + pb) * DD + 4 * q4]);
                pacc.x = fmaf(w, v.x, pacc.x);
                pacc.y = fmaf(w, v.y, pacc.y);
                pacc.z = fmaf(w, v.z, pacc.z);
                pacc.w = fmaf(w, v.w, pacc.w);
            }
        } else if (tid < 104) {
            const int bcol = tid - 100;
            float d = 0.0f;
            #pragma unroll
            for (int s = 0; s < SCH; ++s) d += wexp[s * NBCOL + bcol];
            dreg += d;
        }

        // ---- 4. next chunk fully landed (issued one full compute phase ago) ----
        WAIT_VM0;
        __builtin_amdgcn_s_barrier();     // B2: next buffer ready; fs[cur] reads done
        __builtin_amdgcn_sched_barrier(0);
        cur ^= 1;
    }

    // ---- epilogue: normalize and write pooled ----
    if (tid >= 100 && tid < 104) den_s[tid - 100] = dreg;
    __syncthreads();
    if (pact) {
        const float rd = 1.0f / den_s[pb];
        float4 o;
        o.x = pacc.x * rd;
        o.y = pacc.y * rd;
        o.z = pacc.z * rd;
        o.w = pacc.w * rd;
        *reinterpret_cast<float4*>(&out[(size_t)(b0 + pb) * DD + 4 * q4]) = o;
    }
}

extern "C" void kernel_launch(void* const* d_in, const int* in_sizes, int n_in,
                              void* d_out, int out_size, void* d_ws, size_t ws_size,
                              hipStream_t stream) {
    const float* f    = (const float*)d_in[0];   // [256, 4096, 100]
    const float* h    = (const float*)d_in[1];   // [2, 4096, 50]
    const float* W    = (const float*)d_in[2];   // [100, 100]
    const float* bias = (const float*)d_in[3];   // [1, 100]
    const float* cw   = (const float*)d_in[4];   // [100, 1]
    float* out = (float*)d_out;                  // [pooled 409600 | h 409600]

    uint4* wsf = (uint4*)d_ws;                   // 28,672 B (well within ws)

    prep_wfrag<<<7, 256, 0, stream>>>(W, wsf);
    fused_sent_attn<<<BATCH / NBCOL, 256, 0, stream>>>(f, wsf, bias, cw, h, out);
}

// Round 11
// 105.995 us; speedup vs baseline: 4.3977x; 4.3977x over previous
//
#include <hip/hip_runtime.h>
#include <hip/hip_bf16.h>

#define SEQ 256
#define BATCH 4096
#define DD 100
#define SB (BATCH * DD)             // floats between s-planes
#define NBCOL 8                     // batch columns per block
#define SCH 8                       // s-planes per chunk
#define NCHUNK (SEQ / SCH)          // 32
#define ROWS (SCH * NBCOL)          // 64 rows per chunk (row = s_local*8 + b_local)
#define SLAB_B (NBCOL * DD * 4)     // 3200 B per s-slab
#define CH_BYTES (ROWS * DD * 4)    // 25600 B per chunk

typedef __attribute__((ext_vector_type(8))) short bf16x8;
typedef __attribute__((ext_vector_type(4))) float f32x4;
typedef __attribute__((ext_vector_type(4))) unsigned u32x4;

#define WAIT_VM7  asm volatile("s_waitcnt vmcnt(7)" ::: "memory")
#define WAIT_VM0  asm volatile("s_waitcnt vmcnt(0)" ::: "memory")
#define WAIT_LGKM asm volatile("s_waitcnt lgkmcnt(0)" ::: "memory")

__device__ __forceinline__ short f2bf(float x) {
    __hip_bfloat16 hv = __float2bfloat16(x);
    return *reinterpret_cast<short*>(&hv);
}
__device__ __forceinline__ float bf2f_lo(unsigned int u) {
    return __builtin_bit_cast(float, u << 16);
}
__device__ __forceinline__ float bf2f_hi(unsigned int u) {
    return __builtin_bit_cast(float, u & 0xffff0000u);
}
// accurate tanh (outer score only)
__device__ __forceinline__ float fast_tanh(float x) {
    float ax = fabsf(x);
    float e  = __expf(-2.0f * ax);
    float t  = (1.0f - e) * __builtin_amdgcn_rcpf(1.0f + e);
    return copysignf(t, x);
}
// Pade(3,2) tanh, clamped (inner activations; error budget verified r7-r9)
__device__ __forceinline__ float pade_tanh(float x) {
    const float x2  = x * x;
    const float num = x * (27.0f + x2);
    const float den = fmaf(9.0f, x2, 27.0f);
    const float t   = num * __builtin_amdgcn_rcpf(den);
    return fminf(1.0f, fmaxf(-1.0f, t));
}
// (bf16(hi)<<16) | bf16(lo), truncating — one v_perm_b32
__device__ __forceinline__ unsigned pack_bf2(float lo, float hi) {
    return __builtin_amdgcn_perm(__builtin_bit_cast(unsigned, hi),
                                 __builtin_bit_cast(unsigned, lo),
                                 0x07060302u);
}

// ---- prep: pack W [DD x DD] fp32 -> MFMA B-fragments (bf16, zero-padded) ----
// frag (n,t): cols [16n,16n+16), k [32t,32t+32). lane l: col = 16n+(l&15),
// k = 32t + 8*(l>>4) + e. Layout verified rounds 2-10.
__global__ void prep_wfrag(const float* __restrict__ W, uint4* __restrict__ wsf) {
    const int idx = blockIdx.x * 256 + threadIdx.x;
    if (idx >= 28 * 64) return;
    const int l  = idx & 63;
    const int ft = idx >> 6;
    const int t  = ft & 3;
    const int n  = ft >> 2;
    const int col   = 16 * n + (l & 15);
    const int kbase = 32 * t + 8 * (l >> 4);
    unsigned short v[8];
    #pragma unroll
    for (int e = 0; e < 8; ++e) {
        const int k = kbase + e;
        const float w = (col < DD && k < DD) ? W[k * DD + col] : 0.0f;
        v[e] = (unsigned short)f2bf(w);
    }
    uint4 u;
    u.x = (unsigned)v[0] | ((unsigned)v[1] << 16);
    u.y = (unsigned)v[2] | ((unsigned)v[3] << 16);
    u.z = (unsigned)v[4] | ((unsigned)v[5] << 16);
    u.w = (unsigned)v[6] | ((unsigned)v[7] << 16);
    wsf[ft * 64 + l] = u;
}

// Direct global->LDS staging of one 25600B chunk, EXACTLY 7 loads per wave:
//  - 24 slots of 1KB (64 lanes x 16B): slot q = wid + 4r, r = 0..5
//  - final 1KB split 4 ways: 256B per wave (64 lanes x 4B)
__device__ __forceinline__ void stage_chunk(const float* __restrict__ f,
                                            int s0, int b0, float* lbase,
                                            int wid, int lane) {
    #pragma unroll
    for (int r = 0; r < 6; ++r) {
        const int q   = wid + 4 * r;               // 0..23, wave-uniform
        const int L   = (q << 10) + (lane << 4);
        const int s   = L / SLAB_B;
        const int rem = L - s * SLAB_B;
        const float* gp = f + (size_t)(s0 + s) * SB + (size_t)b0 * DD + (rem >> 2);
        __builtin_amdgcn_global_load_lds(
            (const __attribute__((address_space(1))) void*)gp,
            (__attribute__((address_space(3))) void*)((char*)lbase + L),
            16, 0, 0);
    }
    {   // tail: bytes 24576..25599
        const int L   = 24 * 1024 + wid * 256 + lane * 4;
        const int s   = L / SLAB_B;
        const int rem = L - s * SLAB_B;
        const float* gp = f + (size_t)(s0 + s) * SB + (size_t)b0 * DD + (rem >> 2);
        __builtin_amdgcn_global_load_lds(
            (const __attribute__((address_space(1))) void*)gp,
            (__attribute__((address_space(3))) void*)((char*)lbase + L),
            4, 0, 0);
    }
}

__global__ __launch_bounds__(256, 2)
void fused_sent_attn(const float* __restrict__ f,     // [SEQ, BATCH, DD]
                     const uint4* __restrict__ wsf,   // packed W frags (28*64)
                     const float* __restrict__ bias,  // [DD]
                     const float* __restrict__ cw,    // [DD]
                     const float* __restrict__ h,     // [2, BATCH, 50]
                     float* __restrict__ out)         // [pooled | h]
{
    __shared__ __align__(16) float fs[3][ROWS * DD];  // 76,800 B triple buffer
    __shared__ uint4 wlds3[7 * 16];                   // 1,792 B (t=3 W frags)

    const int tid  = threadIdx.x;
    const int lane = tid & 63;
    const int wid  = tid >> 6;
    const int lr   = lane & 15;    // row-in-tile; b = lr&7, s_local = 2*wid+(lr>>3)
    const int g    = lane >> 4;    // k-group
    const int b0   = blockIdx.x * NBCOL;

    // ---- prologue ----
    if (tid < 7 * 16) wlds3[tid] = wsf[(4 * (tid >> 4) + 3) * 64 + (tid & 15)];

    float bias_r[7], cw_r[7];
    #pragma unroll
    for (int n = 0; n < 7; ++n) {
        const int c = 16 * n + lr;
        bias_r[n] = (c < DD) ? bias[c] : 0.0f;
        cw_r[n]   = (c < DD) ? cw[c]   : 0.0f;
    }
    {   // h passthrough: 8 columns x both halves; 200 x float4
        const size_t obase = (size_t)BATCH * DD;
        const size_t HB = (size_t)BATCH * 50;
        if (tid < 200) {
            const int half = tid / 100, rem = tid - 100 * half;
            const float4* hs = reinterpret_cast<const float4*>(h + half * HB + (size_t)b0 * 50);
            float4* od = reinterpret_cast<float4*>(out + obase + half * HB + (size_t)b0 * 50);
            od[rem] = hs[rem];
        }
    }
    // W fragments t=0..2 -> registers (84 VGPR); t=3 stays in LDS
    bf16x8 wr[21];
    #pragma unroll
    for (int n = 0; n < 7; ++n)
        #pragma unroll
        for (int t = 0; t < 3; ++t)
            wr[3 * n + t] = *reinterpret_cast<const bf16x8*>(&wsf[(4 * n + t) * 64 + lane]);
    WAIT_VM0;                       // h-stores + wr + bias/cw drained -> clean vm count

    stage_chunk(f, 0,   b0, fs[0], wid, lane);
    stage_chunk(f, SCH, b0, fs[1], wid, lane);
    WAIT_VM7;                       // chunk0 landed, chunk1 in flight
    WAIT_LGKM;                      // wlds3 writes done
    __builtin_amdgcn_s_barrier();
    __builtin_amdgcn_sched_barrier(0);

    // per-lane pooled partial: column b = lr&7 fixed across chunks, d = 32t+8g+e
    float pacc[4][8] = {{0}};
    float dreg = 0.0f;

    int cur = 0;
    for (int jc = 0; jc < NCHUNK; ++jc) {
        const int nxt2 = (cur + 2 >= 3) ? cur - 1 : cur + 2;

        // ---- 1. issue chunk jc+2 (in flight across the whole iteration) ----
        if (jc + 2 < NCHUNK)
            stage_chunk(f, (jc + 2) * SCH, b0, fs[nxt2], wid, lane);

        // ---- 2. scores for this wave's 16 rows ----
        const float* rp = &fs[cur][(16 * wid + lr) * DD];
        bf16x8 a[4];
        #pragma unroll
        for (int t = 0; t < 3; ++t) {
            const float4 u0 = *reinterpret_cast<const float4*>(rp + 32 * t + 8 * g);
            const float4 u1 = *reinterpret_cast<const float4*>(rp + 32 * t + 8 * g + 4);
            u32x4 pk = {pack_bf2(u0.x, u0.y), pack_bf2(u0.z, u0.w),
                        pack_bf2(u1.x, u1.y), pack_bf2(u1.z, u1.w)};
            a[t] = __builtin_bit_cast(bf16x8, pk);
        }
        {
            u32x4 pk = {0u, 0u, 0u, 0u};
            if (g == 0) {
                const float4 u0 = *reinterpret_cast<const float4*>(rp + 96);
                pk.x = pack_bf2(u0.x, u0.y);
                pk.y = pack_bf2(u0.z, u0.w);
            }
            a[3] = __builtin_bit_cast(bf16x8, pk);
        }

        float scp[4] = {0, 0, 0, 0};
        #pragma unroll
        for (int n = 0; n < 7; ++n) {
            bf16x8 b3 = {0, 0, 0, 0, 0, 0, 0, 0};
            if (g == 0) b3 = *reinterpret_cast<const bf16x8*>(&wlds3[16 * n + lr]);
            f32x4 acc = {bias_r[n], bias_r[n], bias_r[n], bias_r[n]};
            acc = __builtin_amdgcn_mfma_f32_16x16x32_bf16(a[0], wr[3 * n + 0], acc, 0, 0, 0);
            acc = __builtin_amdgcn_mfma_f32_16x16x32_bf16(a[1], wr[3 * n + 1], acc, 0, 0, 0);
            acc = __builtin_amdgcn_mfma_f32_16x16x32_bf16(a[2], wr[3 * n + 2], acc, 0, 0, 0);
            acc = __builtin_amdgcn_mfma_f32_16x16x32_bf16(a[3], b3,            acc, 0, 0, 0);
            #pragma unroll
            for (int r = 0; r < 4; ++r)
                scp[r] = fmaf(pade_tanh(acc[r]), cw_r[n], scp[r]);
        }
        // reduce over the 16 col-lanes: scp[r] -> S[row 4g+r], all lanes of group g
        #pragma unroll
        for (int r = 0; r < 4; ++r) {
            float v = scp[r];
            v += __shfl_xor(v, 1);
            v += __shfl_xor(v, 2);
            v += __shfl_xor(v, 4);
            v += __shfl_xor(v, 8);
            scp[r] = v;
        }
        // broadcast: this lane needs S[lr] (its own row) = group lr>>2, reg lr&3
        {
            const int src = (lr >> 2) << 4;
            const float tt0 = __shfl(scp[0], src);
            const float tt1 = __shfl(scp[1], src);
            const float tt2 = __shfl(scp[2], src);
            const float tt3 = __shfl(scp[3], src);
            const float ta = (lr & 1) ? tt1 : tt0;
            const float tb = (lr & 1) ? tt3 : tt2;
            const float Srow = (lr & 2) ? tb : ta;
            const float w = __expf(fast_tanh(Srow));

            // ---- 3. pool in registers: pacc[d] += w * f[row, d] ----
            #pragma unroll
            for (int t = 0; t < 4; ++t) {
                const u32x4 u = __builtin_bit_cast(u32x4, a[t]);
                #pragma unroll
                for (int j = 0; j < 4; ++j) {
                    pacc[t][2 * j]     = fmaf(w, bf2f_lo(u[j]), pacc[t][2 * j]);
                    pacc[t][2 * j + 1] = fmaf(w, bf2f_hi(u[j]), pacc[t][2 * j + 1]);
                }
            }
            dreg += w;
        }

        // ---- 4. single sync point: chunk jc+1 landed, fs[cur] reads done ----
        if (jc + 2 < NCHUNK) { WAIT_VM7; } else { WAIT_VM0; }
        __builtin_amdgcn_s_barrier();
        __builtin_amdgcn_sched_barrier(0);
        cur = (cur + 1 >= 3) ? 0 : cur + 1;
    }

    // ---- epilogue: combine the two s-rows per b (lr ^ 8), then waves ----
    float pv[4][8];
    #pragma unroll
    for (int t = 0; t < 4; ++t)
        #pragma unroll
        for (int e = 0; e < 8; ++e)
            pv[t][e] = pacc[t][e] + __shfl_xor(pacc[t][e], 8);
    const float dv = dreg + __shfl_xor(dreg, 8);

    float* pool_sc = &fs[0][0];      // reuse dead buffers: [4][8][104] = 13,312 B
    float* den_sc  = &fs[1][0];      // [4][8]
    if (lr < 8) {
        float* dst = pool_sc + (wid * 8 + lr) * 104;
        #pragma unroll
        for (int t = 0; t < 3; ++t) {
            const int d0 = 32 * t + 8 * g;
            const float4 v0 = {pv[t][0], pv[t][1], pv[t][2], pv[t][3]};
            const float4 v1 = {pv[t][4], pv[t][5], pv[t][6], pv[t][7]};
            *reinterpret_cast<float4*>(dst + d0)     = v0;
            *reinterpret_cast<float4*>(dst + d0 + 4) = v1;
        }
        if (g == 0) {
            const float4 v0 = {pv[3][0], pv[3][1], pv[3][2], pv[3][3]};
            *reinterpret_cast<float4*>(dst + 96) = v0;
            den_sc[wid * 8 + lr] = dv;
        }
    }
    __syncthreads();

    if (tid < 200) {
        const int pb = tid / 25, q4 = tid % 25;
        f32x4 acc = {0.0f, 0.0f, 0.0f, 0.0f};
        float den = 0.0f;
        #pragma unroll
        for (int w2 = 0; w2 < 4; ++w2) {
            const f32x4 v = *reinterpret_cast<const f32x4*>(
                pool_sc + (w2 * 8 + pb) * 104 + 4 * q4);
            acc.x += v.x; acc.y += v.y; acc.z += v.z; acc.w += v.w;
            den += den_sc[w2 * 8 + pb];
        }
        const float rd = 1.0f / den;
        float4 o;
        o.x = acc.x * rd; o.y = acc.y * rd; o.z = acc.z * rd; o.w = acc.w * rd;
        *reinterpret_cast<float4*>(&out[(size_t)(b0 + pb) * DD + 4 * q4]) = o;
    }
}

extern "C" void kernel_launch(void* const* d_in, const int* in_sizes, int n_in,
                              void* d_out, int out_size, void* d_ws, size_t ws_size,
                              hipStream_t stream) {
    const float* f    = (const float*)d_in[0];   // [256, 4096, 100]
    const float* h    = (const float*)d_in[1];   // [2, 4096, 50]
    const float* W    = (const float*)d_in[2];   // [100, 100]
    const float* bias = (const float*)d_in[3];   // [1, 100]
    const float* cw   = (const float*)d_in[4];   // [100, 1]
    float* out = (float*)d_out;                  // [pooled 409600 | h 409600]

    uint4* wsf = (uint4*)d_ws;                   // 28,672 B (known-safe ws usage)

    prep_wfrag<<<7, 256, 0, stream>>>(W, wsf);
    fused_sent_attn<<<BATCH / NBCOL, 256, 0, stream>>>(f, wsf, bias, cw, h, out);
}

// Round 12
// 96.842 us; speedup vs baseline: 4.8134x; 1.0945x over previous
//
#include <hip/hip_runtime.h>
#include <hip/hip_bf16.h>

#define SEQ 256
#define BATCH 4096
#define DD 100
#define SB (BATCH * DD)             // floats between s-planes
#define NBCOL 8                     // batch columns per block
#define SCH 8                       // s-planes per chunk
#define NCHUNK (SEQ / SCH)          // 32
#define ROWS (SCH * NBCOL)          // 64 rows per chunk (row = s_local*8 + b_local)
#define SLAB_B (NBCOL * DD * 4)     // 3200 B per s-slab
#define WROWS_B (16 * DD * 4)       // 6400 B: one wave's 16 rows

typedef __attribute__((ext_vector_type(8))) short bf16x8;
typedef __attribute__((ext_vector_type(4))) float f32x4;
typedef __attribute__((ext_vector_type(4))) unsigned u32x4;

#define WAIT_VM7  asm volatile("s_waitcnt vmcnt(7)" ::: "memory")
#define WAIT_VM0  asm volatile("s_waitcnt vmcnt(0)" ::: "memory")
#define WAIT_LGKM asm volatile("s_waitcnt lgkmcnt(0)" ::: "memory")

__device__ __forceinline__ short f2bf(float x) {
    __hip_bfloat16 hv = __float2bfloat16(x);
    return *reinterpret_cast<short*>(&hv);
}
__device__ __forceinline__ float bf2f_lo(unsigned int u) {
    return __builtin_bit_cast(float, u << 16);
}
__device__ __forceinline__ float bf2f_hi(unsigned int u) {
    return __builtin_bit_cast(float, u & 0xffff0000u);
}
// accurate tanh (outer score only)
__device__ __forceinline__ float fast_tanh(float x) {
    float ax = fabsf(x);
    float e  = __expf(-2.0f * ax);
    float t  = (1.0f - e) * __builtin_amdgcn_rcpf(1.0f + e);
    return copysignf(t, x);
}
// Pade(3,2) tanh, clamped (inner activations; error budget verified r7-r11)
__device__ __forceinline__ float pade_tanh(float x) {
    const float x2  = x * x;
    const float num = x * (27.0f + x2);
    const float den = fmaf(9.0f, x2, 27.0f);
    const float t   = num * __builtin_amdgcn_rcpf(den);
    return fminf(1.0f, fmaxf(-1.0f, t));
}
// (bf16(hi)<<16) | bf16(lo), truncating — one v_perm_b32
__device__ __forceinline__ unsigned pack_bf2(float lo, float hi) {
    return __builtin_amdgcn_perm(__builtin_bit_cast(unsigned, hi),
                                 __builtin_bit_cast(unsigned, lo),
                                 0x07060302u);
}

// ---- prep: pack W [DD x DD] fp32 -> MFMA B-fragments (bf16, zero-padded) ----
// frag (n,t): cols [16n,16n+16), k [32t,32t+32). lane l: col = 16n+(l&15),
// k = 32t + 8*(l>>4) + e. Layout verified rounds 2-11.
__global__ void prep_wfrag(const float* __restrict__ W, uint4* __restrict__ wsf) {
    const int idx = blockIdx.x * 256 + threadIdx.x;
    if (idx >= 28 * 64) return;
    const int l  = idx & 63;
    const int ft = idx >> 6;
    const int t  = ft & 3;
    const int n  = ft >> 2;
    const int col   = 16 * n + (l & 15);
    const int kbase = 32 * t + 8 * (l >> 4);
    unsigned short v[8];
    #pragma unroll
    for (int e = 0; e < 8; ++e) {
        const int k = kbase + e;
        const float w = (col < DD && k < DD) ? W[k * DD + col] : 0.0f;
        v[e] = (unsigned short)f2bf(w);
    }
    uint4 u;
    u.x = (unsigned)v[0] | ((unsigned)v[1] << 16);
    u.y = (unsigned)v[2] | ((unsigned)v[3] << 16);
    u.z = (unsigned)v[4] | ((unsigned)v[5] << 16);
    u.w = (unsigned)v[6] | ((unsigned)v[7] << 16);
    wsf[ft * 64 + l] = u;
}

// PER-WAVE staging: wave w stages ONLY its own 16 rows (bytes [6400w,6400w+6400)
// of the chunk) with EXACTLY 7 loads: 6 x 1KB dwordx4 + 1 x 256B dword.
// Read ownership == write ownership -> no inter-wave LDS hazard -> no barriers.
__device__ __forceinline__ void stage_rows(const float* __restrict__ f,
                                           int s0, int b0, float* lbase,
                                           int wid, int lane) {
    const int base = WROWS_B * wid;                // wave-uniform
    #pragma unroll
    for (int r = 0; r < 6; ++r) {
        const int L   = base + (r << 10) + (lane << 4);
        const int s   = L / SLAB_B;
        const int rem = L - s * SLAB_B;
        const float* gp = f + (size_t)(s0 + s) * SB + (size_t)b0 * DD + (rem >> 2);
        __builtin_amdgcn_global_load_lds(
            (const __attribute__((address_space(1))) void*)gp,
            (__attribute__((address_space(3))) void*)((char*)lbase + L),
            16, 0, 0);
    }
    {   // tail 256 B: bytes base+6144 .. base+6399
        const int L   = base + 6144 + (lane << 2);
        const int s   = L / SLAB_B;
        const int rem = L - s * SLAB_B;
        const float* gp = f + (size_t)(s0 + s) * SB + (size_t)b0 * DD + (rem >> 2);
        __builtin_amdgcn_global_load_lds(
            (const __attribute__((address_space(1))) void*)gp,
            (__attribute__((address_space(3))) void*)((char*)lbase + L),
            4, 0, 0);
    }
}

__global__ __launch_bounds__(256, 2)
void fused_sent_attn(const float* __restrict__ f,     // [SEQ, BATCH, DD]
                     const uint4* __restrict__ wsf,   // packed W frags (28*64)
                     const float* __restrict__ bias,  // [DD]
                     const float* __restrict__ cw,    // [DD]
                     const float* __restrict__ h,     // [2, BATCH, 50]
                     float* __restrict__ out)         // [pooled | h]
{
    __shared__ __align__(16) float fs[3][ROWS * DD];  // 76,800 B triple buffer
    __shared__ uint4 wlds3[7 * 16];                   // 1,792 B (t=3 W frags)

    const int tid  = threadIdx.x;
    const int lane = tid & 63;
    const int wid  = tid >> 6;
    const int lr   = lane & 15;    // row-in-tile; pooled column b = lr&7
    const int g    = lane >> 4;    // k-group
    const int b0   = blockIdx.x * NBCOL;

    // ---- prologue ----
    if (tid < 7 * 16) wlds3[tid] = wsf[(4 * (tid >> 4) + 3) * 64 + (tid & 15)];

    float bias_r[7], cw_r[7];
    #pragma unroll
    for (int n = 0; n < 7; ++n) {
        const int c = 16 * n + lr;
        bias_r[n] = (c < DD) ? bias[c] : 0.0f;
        cw_r[n]   = (c < DD) ? cw[c]   : 0.0f;
    }
    {   // h passthrough: 8 columns x both halves; 200 x float4
        const size_t obase = (size_t)BATCH * DD;
        const size_t HB = (size_t)BATCH * 50;
        if (tid < 200) {
            const int half = tid / 100, rem = tid - 100 * half;
            const float4* hs = reinterpret_cast<const float4*>(h + half * HB + (size_t)b0 * 50);
            float4* od = reinterpret_cast<float4*>(out + obase + half * HB + (size_t)b0 * 50);
            od[rem] = hs[rem];
        }
    }
    // W fragments t=0..2 -> registers (84 VGPR); t=3 stays in LDS
    bf16x8 wr[21];
    #pragma unroll
    for (int n = 0; n < 7; ++n)
        #pragma unroll
        for (int t = 0; t < 3; ++t)
            wr[3 * n + t] = *reinterpret_cast<const bf16x8*>(&wsf[(4 * n + t) * 64 + lane]);
    WAIT_VM0;                       // h-stores + wr + bias/cw drained -> clean vm count

    stage_rows(f, 0,   b0, fs[0], wid, lane);
    stage_rows(f, SCH, b0, fs[1], wid, lane);
    WAIT_VM7;                       // own chunk0 rows landed, chunk1 in flight
    WAIT_LGKM;                      // wlds3 writes done
    __builtin_amdgcn_s_barrier();   // single prologue barrier (wlds3 visibility)
    __builtin_amdgcn_sched_barrier(0);

    // per-lane pooled partial: column b = lr&7 fixed across chunks, d = 32t+8g+e
    float pacc[4][8] = {{0}};
    float dreg = 0.0f;

    int cur = 0;
    for (int jc = 0; jc < NCHUNK; ++jc) {
        const int nxt2 = (cur + 2 >= 3) ? cur - 1 : cur + 2;

        // ---- 1. issue own rows of chunk jc+2 (in flight all iteration) ----
        if (jc + 2 < NCHUNK)
            stage_rows(f, (jc + 2) * SCH, b0, fs[nxt2], wid, lane);

        // ---- 2. scores for this wave's 16 rows ----
        const float* rp = &fs[cur][(16 * wid + lr) * DD];
        bf16x8 a[4];
        #pragma unroll
        for (int t = 0; t < 3; ++t) {
            const float4 u0 = *reinterpret_cast<const float4*>(rp + 32 * t + 8 * g);
            const float4 u1 = *reinterpret_cast<const float4*>(rp + 32 * t + 8 * g + 4);
            u32x4 pk = {pack_bf2(u0.x, u0.y), pack_bf2(u0.z, u0.w),
                        pack_bf2(u1.x, u1.y), pack_bf2(u1.z, u1.w)};
            a[t] = __builtin_bit_cast(bf16x8, pk);
        }
        {
            u32x4 pk = {0u, 0u, 0u, 0u};
            if (g == 0) {
                const float4 u0 = *reinterpret_cast<const float4*>(rp + 96);
                pk.x = pack_bf2(u0.x, u0.y);
                pk.y = pack_bf2(u0.z, u0.w);
            }
            a[3] = __builtin_bit_cast(bf16x8, pk);
        }

        float scp[4] = {0, 0, 0, 0};
        #pragma unroll
        for (int n = 0; n < 7; ++n) {
            bf16x8 b3 = {0, 0, 0, 0, 0, 0, 0, 0};
            if (g == 0) b3 = *reinterpret_cast<const bf16x8*>(&wlds3[16 * n + lr]);
            f32x4 acc = {bias_r[n], bias_r[n], bias_r[n], bias_r[n]};
            acc = __builtin_amdgcn_mfma_f32_16x16x32_bf16(a[0], wr[3 * n + 0], acc, 0, 0, 0);
            acc = __builtin_amdgcn_mfma_f32_16x16x32_bf16(a[1], wr[3 * n + 1], acc, 0, 0, 0);
            acc = __builtin_amdgcn_mfma_f32_16x16x32_bf16(a[2], wr[3 * n + 2], acc, 0, 0, 0);
            acc = __builtin_amdgcn_mfma_f32_16x16x32_bf16(a[3], b3,            acc, 0, 0, 0);
            #pragma unroll
            for (int r = 0; r < 4; ++r)
                scp[r] = fmaf(pade_tanh(acc[r]), cw_r[n], scp[r]);
        }
        // reduce over 16 col-lanes, then broadcast row lr's score to its lane
        #pragma unroll
        for (int r = 0; r < 4; ++r) {
            float v = scp[r];
            v += __shfl_xor(v, 1);
            v += __shfl_xor(v, 2);
            v += __shfl_xor(v, 4);
            v += __shfl_xor(v, 8);
            scp[r] = v;
        }
        {
            const int src = (lr >> 2) << 4;
            const float tt0 = __shfl(scp[0], src);
            const float tt1 = __shfl(scp[1], src);
            const float tt2 = __shfl(scp[2], src);
            const float tt3 = __shfl(scp[3], src);
            const float ta = (lr & 1) ? tt1 : tt0;
            const float tb = (lr & 1) ? tt3 : tt2;
            const float Srow = (lr & 2) ? tb : ta;
            const float w = __expf(fast_tanh(Srow));

            // ---- 3. pool in registers: pacc[d] += w * f[row, d] ----
            #pragma unroll
            for (int t = 0; t < 4; ++t) {
                const u32x4 u = __builtin_bit_cast(u32x4, a[t]);
                #pragma unroll
                for (int j = 0; j < 4; ++j) {
                    pacc[t][2 * j]     = fmaf(w, bf2f_lo(u[j]), pacc[t][2 * j]);
                    pacc[t][2 * j + 1] = fmaf(w, bf2f_hi(u[j]), pacc[t][2 * j + 1]);
                }
            }
            dreg += w;
        }

        // ---- 4. per-wave wait: own chunk jc+1 rows landed (jc+2 in flight) ----
        // NO BARRIER: each wave only ever touches its own LDS quarter.
        if (jc + 2 < NCHUNK) { WAIT_VM7; } else { WAIT_VM0; }
        __builtin_amdgcn_sched_barrier(0);
        cur = (cur + 1 >= 3) ? 0 : cur + 1;
    }

    // ---- epilogue: combine the two s-rows per b (lr ^ 8), then waves ----
    float pv[4][8];
    #pragma unroll
    for (int t = 0; t < 4; ++t)
        #pragma unroll
        for (int e = 0; e < 8; ++e)
            pv[t][e] = pacc[t][e] + __shfl_xor(pacc[t][e], 8);
    const float dv = dreg + __shfl_xor(dreg, 8);

    // all waves must be done READING fs before it is reused as scratch
    __syncthreads();

    float* pool_sc = &fs[0][0];      // reuse dead buffers: [4][8][104]
    float* den_sc  = &fs[1][0];      // [4][8]
    if (lr < 8) {
        float* dst = pool_sc + (wid * 8 + lr) * 104;
        #pragma unroll
        for (int t = 0; t < 3; ++t) {
            const int d0 = 32 * t + 8 * g;
            const float4 v0 = {pv[t][0], pv[t][1], pv[t][2], pv[t][3]};
            const float4 v1 = {pv[t][4], pv[t][5], pv[t][6], pv[t][7]};
            *reinterpret_cast<float4*>(dst + d0)     = v0;
            *reinterpret_cast<float4*>(dst + d0 + 4) = v1;
        }
        if (g == 0) {
            const float4 v0 = {pv[3][0], pv[3][1], pv[3][2], pv[3][3]};
            *reinterpret_cast<float4*>(dst + 96) = v0;
            den_sc[wid * 8 + lr] = dv;
        }
    }
    __syncthreads();

    if (tid < 200) {
        const int pb = tid / 25, q4 = tid % 25;
        f32x4 acc = {0.0f, 0.0f, 0.0f, 0.0f};
        float den = 0.0f;
        #pragma unroll
        for (int w2 = 0; w2 < 4; ++w2) {
            const f32x4 v = *reinterpret_cast<const f32x4*>(
                pool_sc + (w2 * 8 + pb) * 104 + 4 * q4);
            acc.x += v.x; acc.y += v.y; acc.z += v.z; acc.w += v.w;
            den += den_sc[w2 * 8 + pb];
        }
        const float rd = 1.0f / den;
        float4 o;
        o.x = acc.x * rd; o.y = acc.y * rd; o.z = acc.z * rd; o.w = acc.w * rd;
        *reinterpret_cast<float4*>(&out[(size_t)(b0 + pb) * DD + 4 * q4]) = o;
    }
}

extern "C" void kernel_launch(void* const* d_in, const int* in_sizes, int n_in,
                              void* d_out, int out_size, void* d_ws, size_t ws_size,
                              hipStream_t stream) {
    const float* f    = (const float*)d_in[0];   // [256, 4096, 100]
    const float* h    = (const float*)d_in[1];   // [2, 4096, 50]
    const float* W    = (const float*)d_in[2];   // [100, 100]
    const float* bias = (const float*)d_in[3];   // [1, 100]
    const float* cw   = (const float*)d_in[4];   // [100, 1]
    float* out = (float*)d_out;                  // [pooled 409600 | h 409600]

    uint4* wsf = (uint4*)d_ws;                   // 28,672 B (known-safe ws usage)

    prep_wfrag<<<7, 256, 0, stream>>>(W, wsf);
    fused_sent_attn<<<BATCH / NBCOL, 256, 0, stream>>>(f, wsf, bias, cw, h, out);
}